// Round 1
// baseline (469.163 us; speedup 1.0000x reference)
//
#include <hip/hip_runtime.h>
#include <hip/hip_bf16.h>
#include <stdint.h>

typedef __hip_bfloat16 bf16;
typedef __attribute__((ext_vector_type(8))) short short8;
typedef __attribute__((ext_vector_type(4))) float f32x4;

#define BM 128
#define BN 128

__device__ __forceinline__ unsigned short f2bf_bits(float x) {
    return __builtin_bit_cast(unsigned short, __float2bfloat16(x));
}

// async global->LDS, 16B per lane, LDS dest = wave-uniform base + lane*16
__device__ __forceinline__ void gload_lds16(const bf16* g, bf16* l) {
    __builtin_amdgcn_global_load_lds(
        (const __attribute__((address_space(1))) void*)(const void*)g,
        (__attribute__((address_space(3))) void*)(void*)l,
        16, 0, 0);
}

template <int N>
__device__ __forceinline__ void waitvm() {
    if constexpr (N == 0) asm volatile("s_waitcnt vmcnt(0)" ::: "memory");
    else if constexpr (N == 3) asm volatile("s_waitcnt vmcnt(3)" ::: "memory");
    else if constexpr (N == 4) asm volatile("s_waitcnt vmcnt(4)" ::: "memory");
    else if constexpr (N == 6) asm volatile("s_waitcnt vmcnt(6)" ::: "memory");
    else if constexpr (N == 8) asm volatile("s_waitcnt vmcnt(8)" ::: "memory");
}

// fused prep: [0,8192) feat->bf16 cvt; [8192,11264) W transpose+cvt; [11264] zero lsum
__global__ void prep_kernel(const float* __restrict__ feat, unsigned short* __restrict__ featb,
                            const float* __restrict__ W0, const float* __restrict__ W1,
                            const float* __restrict__ W2, bf16* __restrict__ Wt,
                            float* __restrict__ lsum) {
    const int b = blockIdx.x;
    const int tid = threadIdx.x;
    if (b < 8192) {
        int i = b * 256 + tid;
        float4 v = reinterpret_cast<const float4*>(feat)[i];
        ushort4 o;
        o.x = f2bf_bits(v.x); o.y = f2bf_bits(v.y);
        o.z = f2bf_bits(v.z); o.w = f2bf_bits(v.w);
        reinterpret_cast<ushort4*>(featb)[i] = o;
    } else if (b < 11264) {
        __shared__ float tile[32][33];
        const int b2 = b - 8192;
        const int z = b2 >> 10;
        const int t = b2 & 1023;
        const int bx = t & 31, by = t >> 5;
        const int tx = tid & 31, ty = tid >> 5;
        const float* in = (z == 0) ? W0 : (z == 1) ? W1 : W2;
        bf16* out = Wt + (size_t)z * 1024 * 1024;
        for (int r = ty; r < 32; r += 8)
            tile[r][tx] = in[(size_t)(by * 32 + r) * 1024 + bx * 32 + tx];
        __syncthreads();
        for (int r = ty; r < 32; r += 8)
            out[(size_t)(bx * 32 + r) * 1024 + by * 32 + tx] = __float2bfloat16(tile[tx][r]);
    } else {
        for (int i = tid; i < 8192; i += 256) lsum[i] = 0.f;
    }
}

__global__ void scale_rows(float* __restrict__ out, const float* __restrict__ lsum) {
    int i = blockIdx.x * 256 + threadIdx.x;
    float4 v = reinterpret_cast<float4*>(out)[i];
    float inv = 1.0f / lsum[i >> 8];
    v.x *= inv; v.y *= inv; v.z *= inv; v.w *= inv;
    reinterpret_cast<float4*>(out)[i] = v;
}

// ---------------------------------------------------------------------------
// gemm_bt: legacy 128x128 2-barrier structure (kept for projections + fallback)
// ---------------------------------------------------------------------------
template <int MODE, int KH, int SWAP>
__global__ __launch_bounds__(256, 4)
void gemm_bt(const bf16* __restrict__ A, const bf16* __restrict__ B,
             const float* __restrict__ b0, const float* __restrict__ b1,
             const float* __restrict__ b2, float* __restrict__ lsum,
             bf16* __restrict__ outb, float* __restrict__ outf,
             int M, int N, int K, int ldb, int ldout, float scale) {
    constexpr int TILE = 128 * 32;
    constexpr int SELEMS = (2 * KH * TILE < 9216) ? 9216 : 2 * KH * TILE;
    __shared__ bf16 smem[SELEMS];
    bf16* As = smem;
    bf16* Bs = smem + KH * TILE;

    const int tid  = threadIdx.x;
    const int lane = tid & 63;
    const int wave = tid >> 6;
    const int wm = wave & 1, wn = wave >> 1;
    const int l16  = lane & 15;
    const int quad = lane >> 4;
    long bm0, bn0;
    if (SWAP == 2) {
        const int lin = blockIdx.y * 8 + blockIdx.x;
        const int xcd = lin & 7;
        const int s   = lin >> 3;
        bn0 = (long)(s & 7) * BN;
        bm0 = (long)((s >> 3) * 8 + xcd) * BM;
    } else {
        bm0 = (long)(SWAP ? blockIdx.y : blockIdx.x) * BM;
        bn0 = (long)(SWAP ? blockIdx.x : blockIdx.y) * BN;
    }

    const bf16* Ause = A;
    const bf16* Buse = B;
    bf16* oz = outb;
    int  ldo = ldout;
    int  z   = 0;
    if (MODE == 0) {
        z = blockIdx.z;
        if (z == 2) {
            bm0  = (long)blockIdx.y * BM;
            bn0  = (long)blockIdx.x * BN;
            Ause = B + (size_t)2 * N * K;
            Buse = A;
            oz   = outb + (size_t)2 * M * ldout;
            ldo  = M;
        } else {
            Buse = B + (size_t)z * N * K;
            oz   = outb + (size_t)z * M * ldout;
        }
    }

    const int lrow = lane >> 2;
    const int lcol = (lane & 3) * 8;
    const bf16* gA[2][KH];
    const bf16* gB[2][KH];
    bf16* lA[2][KH];
    bf16* lB[2][KH];
#pragma unroll
    for (int u = 0; u < 2; u++)
#pragma unroll
        for (int h = 0; h < KH; h++) {
            gA[u][h] = Ause + (size_t)(bm0 + wave * 32 + u * 16 + lrow) * K + h * 32 + lcol;
            gB[u][h] = Buse + (size_t)(bn0 + wave * 32 + u * 16 + lrow) * ldb + h * 32 + lcol;
            lA[u][h] = As + h * TILE + (wave * 32 + u * 16) * 32;
            lB[u][h] = Bs + h * TILE + (wave * 32 + u * 16) * 32;
        }

    const bf16* Ard = As + (wm * 64 + l16) * 32 + quad * 8;
    const bf16* Brd = Bs + (wn * 64 + l16) * 32 + quad * 8;

    f32x4 acc[4][4];
    const f32x4 zero = {0.f, 0.f, 0.f, 0.f};
#pragma unroll
    for (int i = 0; i < 4; i++)
#pragma unroll
        for (int j = 0; j < 4; j++) acc[i][j] = zero;

    for (int k0 = 0; k0 < K; k0 += KH * 32) {
        __syncthreads();
#pragma unroll
        for (int u = 0; u < 2; u++)
#pragma unroll
            for (int h = 0; h < KH; h++) {
                gload_lds16(gA[u][h] + k0, lA[u][h]);
                gload_lds16(gB[u][h] + k0, lB[u][h]);
            }
        __syncthreads();
#pragma unroll
        for (int h = 0; h < KH; h++) {
            short8 af[4], bfr[4];
#pragma unroll
            for (int mi = 0; mi < 4; mi++)
                af[mi] = *reinterpret_cast<const short8*>(Ard + h * TILE + mi * 16 * 32);
#pragma unroll
            for (int ni = 0; ni < 4; ni++)
                bfr[ni] = *reinterpret_cast<const short8*>(Brd + h * TILE + ni * 16 * 32);
#pragma unroll
            for (int mi = 0; mi < 4; mi++)
#pragma unroll
                for (int ni = 0; ni < 4; ni++)
                    acc[mi][ni] = __builtin_amdgcn_mfma_f32_16x16x32_bf16(af[mi], bfr[ni], acc[mi][ni], 0, 0, 0);
        }
    }

    if (MODE == 0 || MODE == 1) {
        __syncthreads();
        float bcol[4];
        if (MODE == 0 && z < 2) {
            const float* bias = (z == 0) ? b0 : b1;
#pragma unroll
            for (int ni = 0; ni < 4; ni++) bcol[ni] = bias[bn0 + wn * 64 + l16 + ni * 16];
        }
#pragma unroll
        for (int mi = 0; mi < 4; mi++) {
            bf16* eb = smem + ((wave << 1) | (mi & 1)) * 1152;
#pragma unroll
            for (int r = 0; r < 4; r++) {
                float s = 0.f;
                float brow = 0.f;
                if (MODE == 0 && z == 2) brow = b2[bm0 + wm * 64 + mi * 16 + quad * 4 + r];
#pragma unroll
                for (int ni = 0; ni < 4; ni++) {
                    float v = acc[mi][ni][r];
                    if (MODE == 0) v += (z == 2) ? brow : bcol[ni];
                    else { v = __expf(v * scale); s += v; }
                    eb[(quad * 4 + r) * 72 + ni * 16 + l16] = __float2bfloat16(v);
                }
                if (MODE == 1) {
                    s += __shfl_xor(s, 1);
                    s += __shfl_xor(s, 2);
                    s += __shfl_xor(s, 4);
                    s += __shfl_xor(s, 8);
                    if (l16 == 0) atomicAdd(&lsum[bm0 + wm * 64 + mi * 16 + quad * 4 + r], s);
                }
            }
            asm volatile("s_waitcnt lgkmcnt(0)" ::: "memory");
#pragma unroll
            for (int p = 0; p < 2; p++) {
                int r2 = p * 8 + (lane >> 3);
                int c2 = (lane & 7) * 8;
                short8 val = *reinterpret_cast<const short8*>(eb + r2 * 72 + c2);
                *reinterpret_cast<short8*>(
                    oz + (size_t)(bm0 + wm * 64 + mi * 16 + r2) * ldo + bn0 + wn * 64 + c2) = val;
            }
        }
    } else {
        const int rb2 = wm * 64 + quad * 4;
        const int cb2 = wn * 64 + l16;
#pragma unroll
        for (int mi = 0; mi < 4; mi++)
#pragma unroll
            for (int r = 0; r < 4; r++) {
                long row = bm0 + rb2 + mi * 16 + r;
                float mul = (MODE == 3) ? 1.0f / lsum[row] : 0.f;
#pragma unroll
                for (int ni = 0; ni < 4; ni++) {
                    long col = bn0 + cb2 + ni * 16;
                    if (MODE == 3) outf[row * ldout + col] = acc[mi][ni][r] * mul;
                    else           outf[row * ldout + col] += acc[mi][ni][r];
                }
            }
    }
}

// ---------------------------------------------------------------------------
// gemm8p: 8-phase counted-vmcnt structure (T3+T4+T5), BK=32, 4-deep LDS ring,
// lead-3 prefetch (never vmcnt(0) in steady state), 512 threads / 8 waves.
// MODE 1: P = exp(q k^T * scale) -> bf16 + atomic row sums.  256x256 tile.
// MODE 3: out = (P v^T) / lsum.                              256x128 tile,
//         XCD-grouped grid (8 col-tiles of one P row-slab -> one XCD L2).
// LDS layout per ring slot: A [BM][32] then B [BN][32] (64 B row stride =>
// ds_read_b128 over 16 consecutive rows is 1024 B contiguous, conflict-free;
// linear layout matches global_load_lds wave-uniform-base+lane*16 rule).
// ---------------------------------------------------------------------------
template <int MODE>
__global__ __launch_bounds__(512, 2)
void gemm8p(const bf16* __restrict__ A, const bf16* __restrict__ B,
            float* __restrict__ lsum, bf16* __restrict__ outb,
            float* __restrict__ outf, int M, int N, int K,
            int ldb, int ldout, float scale) {
    constexpr int TM = 256;
    constexpr int TN = (MODE == 1) ? 256 : 128;
    constexpr int WN = (MODE == 1) ? 4 : 2;     // waves along N
    constexpr int FM = (MODE == 1) ? 8 : 4;     // 16-row frags per wave
    constexpr int FN = 4;                       // 16-col frags per wave
    constexpr int JP = FM / 4;                  // phases per K-tile
    constexpr int IB = TN / 128;                // B gloads per tile (A = 2)
    constexpr int LT = 2 + IB;                  // gloads per tile
    constexpr int TA = TM * 32;
    constexpr int TB = TN * 32;
    constexpr int SB = TA + TB;                 // ring slot elems
    __shared__ __align__(16) bf16 smem[4 * SB];

    const int tid  = threadIdx.x;
    const int lane = tid & 63;
    const int wave = tid >> 6;
    const int wm   = wave / WN;
    const int wn   = wave % WN;
    const int l16  = lane & 15;
    const int quad = lane >> 4;
    const int lrow = lane >> 2;
    const int lcol = (lane & 3) * 8;

    long bm0, bn0;
    if constexpr (MODE == 3) {
        const int lin = blockIdx.y * 8 + blockIdx.x;  // x fastest in dispatch
        const int xcd = lin & 7;
        const int s   = lin >> 3;
        bn0 = (long)(s & 7) * TN;               // col tile 0..7
        bm0 = (long)((s >> 3) * 8 + xcd) * TM;  // row slab, XCD-grouped
    } else {
        bm0 = (long)blockIdx.x * TM;
        bn0 = (long)blockIdx.y * TN;
    }

    // staging: instr i covers rows [i*128 + wave*16, +16); lane l -> row l>>2,
    // cols (l&3)*8..+8.  LDS dest offsets are wave-uniform.
    const bf16* gA0 = A + (size_t)(bm0 + wave * 16 + lrow) * K + lcol;
    const bf16* gA1 = A + (size_t)(bm0 + 128 + wave * 16 + lrow) * K + lcol;
    const bf16* gB0 = B + (size_t)(bn0 + wave * 16 + lrow) * ldb + lcol;
    const bf16* gB1 = B + (size_t)(bn0 + (IB == 2 ? 128 : 0) + wave * 16 + lrow) * ldb + lcol;
    const int ldA0 = wave * 512;
    const int ldA1 = 4096 + wave * 512;
    const int ldB0 = TA + wave * 512;
    const int ldB1 = TA + 4096 + wave * 512;

    const int ardo = (wm * (FM * 16) + l16) * 32 + quad * 8;
    const int brdo = TA + (wn * (FN * 16) + l16) * 32 + quad * 8;

    const int T = K / 32;

    f32x4 acc[FM][FN];
    const f32x4 zero = {0.f, 0.f, 0.f, 0.f};
#pragma unroll
    for (int i = 0; i < FM; i++)
#pragma unroll
        for (int j = 0; j < FN; j++) acc[i][j] = zero;

    auto stageA = [&](int u) {
        bf16* sl = smem + (size_t)(u & 3) * SB;
        size_t ko = (size_t)u * 32;
        gload_lds16(gA0 + ko, sl + ldA0);
        gload_lds16(gA1 + ko, sl + ldA1);
    };
    auto stageB = [&](int u) {
        bf16* sl = smem + (size_t)(u & 3) * SB;
        size_t ko = (size_t)u * 32;
        gload_lds16(gB0 + ko, sl + ldB0);
        if constexpr (IB == 2) gload_lds16(gB1 + ko, sl + ldB1);
    };

    // prologue: tiles 0..2 in flight; tile0 resident after vmcnt(2*LT)+barrier
    stageA(0); stageB(0);
    stageA(1); stageB(1);
    stageA(2); stageB(2);
    waitvm<2 * LT>();
    __builtin_amdgcn_s_barrier();

    for (int t = 0; t < T; ++t) {
        const bf16* sl = smem + (size_t)(t & 3) * SB;
        short8 bfr[4];
#pragma unroll
        for (int jp = 0; jp < JP; ++jp) {
            short8 af[4];
            if (jp == 0) {
#pragma unroll
                for (int n = 0; n < 4; n++)
                    bfr[n] = *reinterpret_cast<const short8*>(sl + brdo + n * 512);
            }
#pragma unroll
            for (int m = 0; m < 4; m++)
                af[m] = *reinterpret_cast<const short8*>(sl + ardo + (jp * 4 + m) * 512);
            // prefetch tile t+3 (slot (t+3)&3 == (t-1)&3: dead since t-1's end)
            if (t + 3 < T) {
                if constexpr (JP == 1) { stageA(t + 3); stageB(t + 3); }
                else {
                    if (jp == 0) stageA(t + 3);
                    else         stageB(t + 3);
                }
            }
            // residency for tile t+1: leave tiles t+2,t+3 (2*LT loads) in flight
            if (jp == JP - 1 && t + 1 < T) {
                if (t + 3 < T)      waitvm<2 * LT>();
                else if (t + 2 < T) waitvm<LT>();
                else                waitvm<0>();
            }
            __builtin_amdgcn_s_barrier();
            asm volatile("s_waitcnt lgkmcnt(0)" ::: "memory");
            __builtin_amdgcn_sched_barrier(0);
            __builtin_amdgcn_s_setprio(1);
#pragma unroll
            for (int m = 0; m < 4; m++)
#pragma unroll
                for (int n = 0; n < 4; n++)
                    acc[jp * 4 + m][n] = __builtin_amdgcn_mfma_f32_16x16x32_bf16(
                        af[m], bfr[n], acc[jp * 4 + m][n], 0, 0, 0);
            __builtin_amdgcn_s_setprio(0);
            __builtin_amdgcn_s_barrier();
        }
    }
    __syncthreads();  // ring dead; reuse smem for epilogue staging

    // C/D layout (m89/m91): col = lane&15, row = quad*4 + r
    if constexpr (MODE == 1) {
#pragma unroll
        for (int mi = 0; mi < FM; mi++) {
            bf16* eb = smem + ((wave << 1) | (mi & 1)) * 1152;
#pragma unroll
            for (int r = 0; r < 4; r++) {
                float s = 0.f;
#pragma unroll
                for (int ni = 0; ni < 4; ni++) {
                    float v = __expf(acc[mi][ni][r] * scale);
                    s += v;
                    eb[(quad * 4 + r) * 72 + ni * 16 + l16] = __float2bfloat16(v);
                }
                s += __shfl_xor(s, 1);
                s += __shfl_xor(s, 2);
                s += __shfl_xor(s, 4);
                s += __shfl_xor(s, 8);
                if (l16 == 0)
                    atomicAdd(&lsum[bm0 + wm * 128 + mi * 16 + quad * 4 + r], s);
            }
            asm volatile("s_waitcnt lgkmcnt(0)" ::: "memory");
#pragma unroll
            for (int p = 0; p < 2; p++) {
                int r2 = p * 8 + (lane >> 3);
                int c2 = (lane & 7) * 8;
                short8 val = *reinterpret_cast<const short8*>(eb + r2 * 72 + c2);
                *reinterpret_cast<short8*>(
                    outb + (size_t)(bm0 + wm * 128 + mi * 16 + r2) * ldout + bn0 + wn * 64 + c2) = val;
            }
        }
    } else {
#pragma unroll
        for (int mi = 0; mi < FM; mi++)
#pragma unroll
            for (int r = 0; r < 4; r++) {
                long row = bm0 + wm * 64 + mi * 16 + quad * 4 + r;
                float mul = 1.0f / lsum[row];
#pragma unroll
                for (int ni = 0; ni < 4; ni++) {
                    long col = bn0 + wn * 64 + ni * 16 + l16;
                    outf[row * ldout + col] = acc[mi][ni][r] * mul;
                }
            }
    }
}

extern "C" void kernel_launch(void* const* d_in, const int* in_sizes, int n_in,
                              void* d_out, int out_size, void* d_ws, size_t ws_size,
                              hipStream_t stream) {
    const float* feat = (const float*)d_in[0];
    const float* Wq   = (const float*)d_in[1];
    const float* bqv  = (const float*)d_in[2];
    const float* Wk   = (const float*)d_in[3];
    const float* bkv  = (const float*)d_in[4];
    const float* Wv   = (const float*)d_in[5];
    const float* bvv  = (const float*)d_in[6];
    float* outp = (float*)d_out;

    const int M = 8192, D = 1024;
    char* ws = (char*)d_ws;
    size_t off = 0;
    auto carve = [&](size_t bytes) -> char* {
        char* r = ws + off;
        off += (bytes + 255) & ~(size_t)255;
        return r;
    };
    bf16* featb = (bf16*)carve((size_t)M * D * 2);
    bf16* Wbt   = (bf16*)carve((size_t)3 * D * D * 2);
    bf16* qk    = (bf16*)carve((size_t)2 * M * D * 2 + (size_t)D * M * 2);
    bf16* vbt   = qk + (size_t)2 * M * D;
    float* lsum = (float*)carve((size_t)M * 4);
    size_t avail = (ws_size > off) ? ws_size - off : 0;

    int C;  // key-chunk width for P
    if      (avail >= (size_t)M * M * 2)    C = M;     // full P, 128 MB
    else if (avail >= (size_t)M * 4096 * 2) C = 4096;
    else if (avail >= (size_t)M * 2048 * 2) C = 2048;
    else                                    C = 1024;
    bf16* Pc = (bf16*)carve((size_t)M * C * 2);

    // 1) fused prep: feat->bf16, W transpose+cvt, lsum zero
    prep_kernel<<<dim3(11265), dim3(256), 0, stream>>>(
        feat, (unsigned short*)featb, Wq, Wk, Wv, Wbt, lsum);
    // 2) merged projection: z=0,1 -> q,k; z=2 -> v^T directly (BK=64)
    gemm_bt<0, 2, 0><<<dim3(M / 128, D / 128, 3), dim3(256), 0, stream>>>(
        featb, Wbt, bqv, bkv, bvv, nullptr, qk, nullptr, M, D, D, D, D, 1.0f);

    const float scale = 0.03125f;  // 1/sqrt(1024)
    bf16* qb = qk;
    bf16* kb = qk + (size_t)M * D;
    if (C == M) {
        // 3a) full P = exp(q k^T/32): 8-phase 256^2, grid 32x32
        gemm8p<1><<<dim3(M / 256, M / 256), dim3(512), 0, stream>>>(
            qb, kb, lsum, Pc, nullptr, M, M, D, D, M, scale);
        // 4a) out = (P v^T)/lsum: 8-phase 256x128, K=8192, XCD-grouped grid
        gemm8p<3><<<dim3(8, M / 256), dim3(512), 0, stream>>>(
            Pc, vbt, lsum, nullptr, outp, M, D, M, M, D, 0.f);
    } else {
        hipMemsetAsync(outp, 0, (size_t)M * D * 4, stream);
        for (int c = 0; c < M / C; c++) {
            gemm_bt<1, 2, 0><<<dim3(M / 128, C / 128), dim3(256), 0, stream>>>(
                qb, kb + (size_t)c * C * D, nullptr, nullptr, nullptr, lsum, Pc, nullptr,
                M, C, D, D, C, scale);
            gemm_bt<2, 2, 1><<<dim3(D / 128, M / 128), dim3(256), 0, stream>>>(
                Pc, vbt + (size_t)c * C, nullptr, nullptr, nullptr, nullptr, nullptr, outp,
                M, D, C, M, D, 0.f);
        }
        scale_rows<<<dim3(M * D / 4 / 256), dim3(256), 0, stream>>>(outp, lsum);
    }
}

// Round 3
// 440.113 us; speedup vs baseline: 1.0660x; 1.0660x over previous
//
#include <hip/hip_runtime.h>
#include <hip/hip_bf16.h>
#include <stdint.h>

typedef __hip_bfloat16 bf16;
typedef __attribute__((ext_vector_type(8))) short short8;
typedef __attribute__((ext_vector_type(4))) float f32x4;

#define BM 128
#define BN 128

__device__ __forceinline__ unsigned short f2bf_bits(float x) {
    return __builtin_bit_cast(unsigned short, __float2bfloat16(x));
}

// async global->LDS, 16B per lane, LDS dest = wave-uniform base + lane*16
__device__ __forceinline__ void gload_lds16(const bf16* g, bf16* l) {
    __builtin_amdgcn_global_load_lds(
        (const __attribute__((address_space(1))) void*)(const void*)g,
        (__attribute__((address_space(3))) void*)(void*)l,
        16, 0, 0);
}

template <int N>
__device__ __forceinline__ void waitvm() {
    if constexpr (N == 0) asm volatile("s_waitcnt vmcnt(0)" ::: "memory");
    else if constexpr (N == 3) asm volatile("s_waitcnt vmcnt(3)" ::: "memory");
    else if constexpr (N == 4) asm volatile("s_waitcnt vmcnt(4)" ::: "memory");
    else if constexpr (N == 6) asm volatile("s_waitcnt vmcnt(6)" ::: "memory");
    else if constexpr (N == 8) asm volatile("s_waitcnt vmcnt(8)" ::: "memory");
}

// fused prep: [0,8192) feat->bf16 cvt; [8192,11264) W transpose+cvt; [11264] zero lsum
__global__ void prep_kernel(const float* __restrict__ feat, unsigned short* __restrict__ featb,
                            const float* __restrict__ W0, const float* __restrict__ W1,
                            const float* __restrict__ W2, bf16* __restrict__ Wt,
                            float* __restrict__ lsum) {
    const int b = blockIdx.x;
    const int tid = threadIdx.x;
    if (b < 8192) {
        int i = b * 256 + tid;
        float4 v = reinterpret_cast<const float4*>(feat)[i];
        ushort4 o;
        o.x = f2bf_bits(v.x); o.y = f2bf_bits(v.y);
        o.z = f2bf_bits(v.z); o.w = f2bf_bits(v.w);
        reinterpret_cast<ushort4*>(featb)[i] = o;
    } else if (b < 11264) {
        __shared__ float tile[32][33];
        const int b2 = b - 8192;
        const int z = b2 >> 10;
        const int t = b2 & 1023;
        const int bx = t & 31, by = t >> 5;
        const int tx = tid & 31, ty = tid >> 5;
        const float* in = (z == 0) ? W0 : (z == 1) ? W1 : W2;
        bf16* out = Wt + (size_t)z * 1024 * 1024;
        for (int r = ty; r < 32; r += 8)
            tile[r][tx] = in[(size_t)(by * 32 + r) * 1024 + bx * 32 + tx];
        __syncthreads();
        for (int r = ty; r < 32; r += 8)
            out[(size_t)(bx * 32 + r) * 1024 + by * 32 + tx] = __float2bfloat16(tile[tx][r]);
    } else {
        for (int i = tid; i < 8192; i += 256) lsum[i] = 0.f;
    }
}

__global__ void scale_rows(float* __restrict__ out, const float* __restrict__ lsum) {
    int i = blockIdx.x * 256 + threadIdx.x;
    float4 v = reinterpret_cast<float4*>(out)[i];
    float inv = 1.0f / lsum[i >> 8];
    v.x *= inv; v.y *= inv; v.z *= inv; v.w *= inv;
    reinterpret_cast<float4*>(out)[i] = v;
}

// ---------------------------------------------------------------------------
// gemm_bt: proven 128x128 2-barrier structure, 4 blocks/CU.
// Used for projections (MODE 0), PV (MODE 3), and the chunked fallback.
// ---------------------------------------------------------------------------
template <int MODE, int KH, int SWAP>
__global__ __launch_bounds__(256, 4)
void gemm_bt(const bf16* __restrict__ A, const bf16* __restrict__ B,
             const float* __restrict__ b0, const float* __restrict__ b1,
             const float* __restrict__ b2, float* __restrict__ lsum,
             bf16* __restrict__ outb, float* __restrict__ outf,
             int M, int N, int K, int ldb, int ldout, float scale) {
    constexpr int TILE = 128 * 32;
    constexpr int SELEMS = (2 * KH * TILE < 9216) ? 9216 : 2 * KH * TILE;
    __shared__ bf16 smem[SELEMS];
    bf16* As = smem;
    bf16* Bs = smem + KH * TILE;

    const int tid  = threadIdx.x;
    const int lane = tid & 63;
    const int wave = tid >> 6;
    const int wm = wave & 1, wn = wave >> 1;
    const int l16  = lane & 15;
    const int quad = lane >> 4;
    long bm0, bn0;
    if (SWAP == 2) {
        const int lin = blockIdx.y * 8 + blockIdx.x;
        const int xcd = lin & 7;
        const int s   = lin >> 3;
        bn0 = (long)(s & 7) * BN;
        bm0 = (long)((s >> 3) * 8 + xcd) * BM;
    } else {
        bm0 = (long)(SWAP ? blockIdx.y : blockIdx.x) * BM;
        bn0 = (long)(SWAP ? blockIdx.x : blockIdx.y) * BN;
    }

    const bf16* Ause = A;
    const bf16* Buse = B;
    bf16* oz = outb;
    int  ldo = ldout;
    int  z   = 0;
    if (MODE == 0) {
        z = blockIdx.z;
        if (z == 2) {
            bm0  = (long)blockIdx.y * BM;
            bn0  = (long)blockIdx.x * BN;
            Ause = B + (size_t)2 * N * K;
            Buse = A;
            oz   = outb + (size_t)2 * M * ldout;
            ldo  = M;
        } else {
            Buse = B + (size_t)z * N * K;
            oz   = outb + (size_t)z * M * ldout;
        }
    }

    const int lrow = lane >> 2;
    const int lcol = (lane & 3) * 8;
    const bf16* gA[2][KH];
    const bf16* gB[2][KH];
    bf16* lA[2][KH];
    bf16* lB[2][KH];
#pragma unroll
    for (int u = 0; u < 2; u++)
#pragma unroll
        for (int h = 0; h < KH; h++) {
            gA[u][h] = Ause + (size_t)(bm0 + wave * 32 + u * 16 + lrow) * K + h * 32 + lcol;
            gB[u][h] = Buse + (size_t)(bn0 + wave * 32 + u * 16 + lrow) * ldb + h * 32 + lcol;
            lA[u][h] = As + h * TILE + (wave * 32 + u * 16) * 32;
            lB[u][h] = Bs + h * TILE + (wave * 32 + u * 16) * 32;
        }

    const bf16* Ard = As + (wm * 64 + l16) * 32 + quad * 8;
    const bf16* Brd = Bs + (wn * 64 + l16) * 32 + quad * 8;

    f32x4 acc[4][4];
    const f32x4 zero = {0.f, 0.f, 0.f, 0.f};
#pragma unroll
    for (int i = 0; i < 4; i++)
#pragma unroll
        for (int j = 0; j < 4; j++) acc[i][j] = zero;

    for (int k0 = 0; k0 < K; k0 += KH * 32) {
        __syncthreads();
#pragma unroll
        for (int u = 0; u < 2; u++)
#pragma unroll
            for (int h = 0; h < KH; h++) {
                gload_lds16(gA[u][h] + k0, lA[u][h]);
                gload_lds16(gB[u][h] + k0, lB[u][h]);
            }
        __syncthreads();
#pragma unroll
        for (int h = 0; h < KH; h++) {
            short8 af[4], bfr[4];
#pragma unroll
            for (int mi = 0; mi < 4; mi++)
                af[mi] = *reinterpret_cast<const short8*>(Ard + h * TILE + mi * 16 * 32);
#pragma unroll
            for (int ni = 0; ni < 4; ni++)
                bfr[ni] = *reinterpret_cast<const short8*>(Brd + h * TILE + ni * 16 * 32);
#pragma unroll
            for (int mi = 0; mi < 4; mi++)
#pragma unroll
                for (int ni = 0; ni < 4; ni++)
                    acc[mi][ni] = __builtin_amdgcn_mfma_f32_16x16x32_bf16(af[mi], bfr[ni], acc[mi][ni], 0, 0, 0);
        }
    }

    if (MODE == 0 || MODE == 1) {
        __syncthreads();
        float bcol[4];
        if (MODE == 0 && z < 2) {
            const float* bias = (z == 0) ? b0 : b1;
#pragma unroll
            for (int ni = 0; ni < 4; ni++) bcol[ni] = bias[bn0 + wn * 64 + l16 + ni * 16];
        }
#pragma unroll
        for (int mi = 0; mi < 4; mi++) {
            bf16* eb = smem + ((wave << 1) | (mi & 1)) * 1152;
#pragma unroll
            for (int r = 0; r < 4; r++) {
                float s = 0.f;
                float brow = 0.f;
                if (MODE == 0 && z == 2) brow = b2[bm0 + wm * 64 + mi * 16 + quad * 4 + r];
#pragma unroll
                for (int ni = 0; ni < 4; ni++) {
                    float v = acc[mi][ni][r];
                    if (MODE == 0) v += (z == 2) ? brow : bcol[ni];
                    else { v = __expf(v * scale); s += v; }
                    eb[(quad * 4 + r) * 72 + ni * 16 + l16] = __float2bfloat16(v);
                }
                if (MODE == 1) {
                    s += __shfl_xor(s, 1);
                    s += __shfl_xor(s, 2);
                    s += __shfl_xor(s, 4);
                    s += __shfl_xor(s, 8);
                    if (l16 == 0) atomicAdd(&lsum[bm0 + wm * 64 + mi * 16 + quad * 4 + r], s);
                }
            }
            asm volatile("s_waitcnt lgkmcnt(0)" ::: "memory");
#pragma unroll
            for (int p = 0; p < 2; p++) {
                int r2 = p * 8 + (lane >> 3);
                int c2 = (lane & 7) * 8;
                short8 val = *reinterpret_cast<const short8*>(eb + r2 * 72 + c2);
                *reinterpret_cast<short8*>(
                    oz + (size_t)(bm0 + wm * 64 + mi * 16 + r2) * ldo + bn0 + wn * 64 + c2) = val;
            }
        }
    } else {
        const int rb2 = wm * 64 + quad * 4;
        const int cb2 = wn * 64 + l16;
#pragma unroll
        for (int mi = 0; mi < 4; mi++)
#pragma unroll
            for (int r = 0; r < 4; r++) {
                long row = bm0 + rb2 + mi * 16 + r;
                float mul = (MODE == 3) ? 1.0f / lsum[row] : 0.f;
#pragma unroll
                for (int ni = 0; ni < 4; ni++) {
                    long col = bn0 + cb2 + ni * 16;
                    if (MODE == 3) outf[row * ldout + col] = acc[mi][ni][r] * mul;
                    else           outf[row * ldout + col] += acc[mi][ni][r];
                }
            }
    }
}

// ---------------------------------------------------------------------------
// gemm2b_qk: QK^T + exp + row-sums.  TM=256 x TN=128, 256 threads / 4 waves
// (each wave owns a 128x64 sub-tile: FM=8, FN=4 -- same per-wave math as the
// round-1-verified MODE-1 epilogue).  Ring-2 LDS (48 KiB) + ~224 total regs
// => 2 independent blocks/CU: cross-block MFMA/LDS/VMEM overlap with no
// shared barriers.  Counted vmcnt(6) = stage(t+2)'s 6 loads left in flight;
// B-region prefetch issued after jp0's post-MFMA barrier (B fully consumed
// in jp0), A-region after jp1's (A halves consumed per-phase).
// ---------------------------------------------------------------------------
__global__ __launch_bounds__(256, 2)
void gemm2b_qk(const bf16* __restrict__ A, const bf16* __restrict__ B,
               float* __restrict__ lsum, bf16* __restrict__ outb,
               int M, int N, int K, int ldb, int ldout, float scale) {
    constexpr int TA = 256 * 32;            // A region elems per slot
    constexpr int SB = TA + 128 * 32;       // slot elems (12288 = 24 KiB)
    __shared__ __align__(16) bf16 smem[2 * SB];

    const int tid  = threadIdx.x;
    const int lane = tid & 63;
    const int wave = tid >> 6;              // 0..3
    const int wm   = wave >> 1;             // 0..1 : row half
    const int wn   = wave & 1;              // 0..1 : col half
    const int l16  = lane & 15;
    const int quad = lane >> 4;
    const int lrow = lane >> 2;
    const int lcol = (lane & 3) * 8;

    const long bm0 = (long)blockIdx.x * 256;
    const long bn0 = (long)blockIdx.y * 128;

    // staging: each gload covers 16 rows (lane -> row l>>2, 16B at (l&3)*16)
    const bf16* gA[4];
    const bf16* gB[2];
    int lA[4], lB[2];
#pragma unroll
    for (int j = 0; j < 4; j++) {
        gA[j] = A + (size_t)(bm0 + j * 64 + wave * 16 + lrow) * K + lcol;
        lA[j] = (j * 64 + wave * 16) * 32;
    }
#pragma unroll
    for (int j = 0; j < 2; j++) {
        gB[j] = B + (size_t)(bn0 + j * 64 + wave * 16 + lrow) * ldb + lcol;
        lB[j] = TA + (j * 64 + wave * 16) * 32;
    }

    const int ardo = (wm * 128 + l16) * 32 + quad * 8;
    const int brdo = TA + (wn * 64 + l16) * 32 + quad * 8;
    const int T = K / 32;

    f32x4 acc[8][4];
    const f32x4 zero = {0.f, 0.f, 0.f, 0.f};
#pragma unroll
    for (int i = 0; i < 8; i++)
#pragma unroll
        for (int j = 0; j < 4; j++) acc[i][j] = zero;

    auto stageA = [&](int u) {
        bf16* sl = smem + (size_t)(u & 1) * SB;
        size_t ko = (size_t)u * 32;
#pragma unroll
        for (int j = 0; j < 4; j++) gload_lds16(gA[j] + ko, sl + lA[j]);
    };
    auto stageB = [&](int u) {
        bf16* sl = smem + (size_t)(u & 1) * SB;
        size_t ko = (size_t)u * 32;
#pragma unroll
        for (int j = 0; j < 2; j++) gload_lds16(gB[j] + ko, sl + lB[j]);
    };

    // prologue: tiles 0,1 in flight (12 loads); tile0 ready after vmcnt(6)
    stageA(0); stageB(0);
    stageA(1); stageB(1);
    waitvm<6>();
    __builtin_amdgcn_s_barrier();

    for (int t = 0; t < T; ++t) {
        const bf16* sl = smem + (size_t)(t & 1) * SB;
        short8 bfr[4];
#pragma unroll
        for (int jp = 0; jp < 2; ++jp) {
            short8 af[4];
            if (jp == 0) {
#pragma unroll
                for (int n = 0; n < 4; n++)
                    bfr[n] = *reinterpret_cast<const short8*>(sl + brdo + n * 512);
            }
#pragma unroll
            for (int m = 0; m < 4; m++)
                af[m] = *reinterpret_cast<const short8*>(sl + ardo + (jp * 4 + m) * 512);
            __builtin_amdgcn_s_barrier();
            asm volatile("s_waitcnt lgkmcnt(0)" ::: "memory");
            __builtin_amdgcn_sched_barrier(0);
            __builtin_amdgcn_s_setprio(1);
#pragma unroll
            for (int m = 0; m < 4; m++)
#pragma unroll
                for (int n = 0; n < 4; n++)
                    acc[jp * 4 + m][n] = __builtin_amdgcn_mfma_f32_16x16x32_bf16(
                        af[m], bfr[n], acc[jp * 4 + m][n], 0, 0, 0);
            __builtin_amdgcn_s_setprio(0);
            __builtin_amdgcn_s_barrier();
            // prefetch into the now-dead region of this slot (2 tiles ahead)
            if (t + 2 < T) {
                if (jp == 0) stageB(t + 2);   // B fully consumed in jp0
                else         stageA(t + 2);   // A fully consumed after jp1
            }
        }
        // tile-end: ensure t+1 resident (leave t+2's 6 loads in flight)
        if (t + 1 < T) {
            if (t + 2 < T) waitvm<6>();
            else           waitvm<0>();
            __builtin_amdgcn_s_barrier();
        }
    }
    __syncthreads();  // ring dead (all gloads drained at t=T-2); reuse smem

    // C/D layout (m89/m91): col = lane&15, row = quad*4 + r
#pragma unroll
    for (int mi = 0; mi < 8; mi++) {
        bf16* eb = smem + ((wave << 1) | (mi & 1)) * 1152;
#pragma unroll
        for (int r = 0; r < 4; r++) {
            float s = 0.f;
#pragma unroll
            for (int ni = 0; ni < 4; ni++) {
                float v = __expf(acc[mi][ni][r] * scale);
                s += v;
                eb[(quad * 4 + r) * 72 + ni * 16 + l16] = __float2bfloat16(v);
            }
            s += __shfl_xor(s, 1);
            s += __shfl_xor(s, 2);
            s += __shfl_xor(s, 4);
            s += __shfl_xor(s, 8);
            if (l16 == 0)
                atomicAdd(&lsum[bm0 + wm * 128 + mi * 16 + quad * 4 + r], s);
        }
        asm volatile("s_waitcnt lgkmcnt(0)" ::: "memory");
#pragma unroll
        for (int p = 0; p < 2; p++) {
            int r2 = p * 8 + (lane >> 3);
            int c2 = (lane & 7) * 8;
            short8 val = *reinterpret_cast<const short8*>(eb + r2 * 72 + c2);
            *reinterpret_cast<short8*>(
                outb + (size_t)(bm0 + wm * 128 + mi * 16 + r2) * ldout + bn0 + wn * 64 + c2) = val;
        }
    }
}

extern "C" void kernel_launch(void* const* d_in, const int* in_sizes, int n_in,
                              void* d_out, int out_size, void* d_ws, size_t ws_size,
                              hipStream_t stream) {
    const float* feat = (const float*)d_in[0];
    const float* Wq   = (const float*)d_in[1];
    const float* bqv  = (const float*)d_in[2];
    const float* Wk   = (const float*)d_in[3];
    const float* bkv  = (const float*)d_in[4];
    const float* Wv   = (const float*)d_in[5];
    const float* bvv  = (const float*)d_in[6];
    float* outp = (float*)d_out;

    const int M = 8192, D = 1024;
    char* ws = (char*)d_ws;
    size_t off = 0;
    auto carve = [&](size_t bytes) -> char* {
        char* r = ws + off;
        off += (bytes + 255) & ~(size_t)255;
        return r;
    };
    bf16* featb = (bf16*)carve((size_t)M * D * 2);
    bf16* Wbt   = (bf16*)carve((size_t)3 * D * D * 2);
    bf16* qk    = (bf16*)carve((size_t)2 * M * D * 2 + (size_t)D * M * 2);
    bf16* vbt   = qk + (size_t)2 * M * D;
    float* lsum = (float*)carve((size_t)M * 4);
    size_t avail = (ws_size > off) ? ws_size - off : 0;

    int C;  // key-chunk width for P
    if      (avail >= (size_t)M * M * 2)    C = M;     // full P, 128 MB
    else if (avail >= (size_t)M * 4096 * 2) C = 4096;
    else if (avail >= (size_t)M * 2048 * 2) C = 2048;
    else                                    C = 1024;
    bf16* Pc = (bf16*)carve((size_t)M * C * 2);

    // 1) fused prep: feat->bf16, W transpose+cvt, lsum zero
    prep_kernel<<<dim3(11265), dim3(256), 0, stream>>>(
        feat, (unsigned short*)featb, Wq, Wk, Wv, Wbt, lsum);
    // 2) merged projection: z=0,1 -> q,k; z=2 -> v^T directly (BK=64)
    gemm_bt<0, 2, 0><<<dim3(M / 128, D / 128, 3), dim3(256), 0, stream>>>(
        featb, Wbt, bqv, bkv, bvv, nullptr, qk, nullptr, M, D, D, D, D, 1.0f);

    const float scale = 0.03125f;  // 1/sqrt(1024)
    bf16* qb = qk;
    bf16* kb = qk + (size_t)M * D;
    if (C == M) {
        // 3a) full P = exp(q k^T/32): 256x128 tiles, 2 blocks/CU, grid 32x64
        gemm2b_qk<<<dim3(M / 256, M / 128), dim3(256), 0, stream>>>(
            qb, kb, lsum, Pc, M, M, D, D, M, scale);
        // 4a) out = (P v^T)/lsum: proven 128x128, K=8192, XCD-swizzled grid
        gemm_bt<3, 2, 2><<<dim3(D / 128, M / 128), dim3(256), 0, stream>>>(
            Pc, vbt, nullptr, nullptr, nullptr, lsum, nullptr, outp, M, D, M, M, D, 0.f);
    } else {
        hipMemsetAsync(outp, 0, (size_t)M * D * 4, stream);
        for (int c = 0; c < M / C; c++) {
            gemm_bt<1, 2, 0><<<dim3(M / 128, C / 128), dim3(256), 0, stream>>>(
                qb, kb + (size_t)c * C * D, nullptr, nullptr, nullptr, lsum, Pc, nullptr,
                M, C, D, D, C, scale);
            gemm_bt<2, 2, 1><<<dim3(D / 128, M / 128), dim3(256), 0, stream>>>(
                Pc, vbt + (size_t)c * C, nullptr, nullptr, nullptr, nullptr, nullptr, outp,
                M, D, C, M, D, 0.f);
        }
        scale_rows<<<dim3(M * D / 4 / 256), dim3(256), 0, stream>>>(outp, lsum);
    }
}